// Round 5
// baseline (160.240 us; speedup 1.0000x reference)
//
#include <hip/hip_runtime.h>

static constexpr int NN   = 50000;    // nodes per batch
static constexpr int NBAT = 4;
static constexpr int NE   = 1600000;  // unique edges
static constexpr int NC   = 1000;
static constexpr int FN   = 64;
static constexpr int FCOL = 32;
static constexpr int HD   = 16;

// two-level partition geometry
static constexpr int NP     = 20;      // level-1 partitions (2500 nodes each)
static constexpr int PNODES = 2500;
static constexpr int PCAP   = 88000;   // mean 80000 (+29 sigma)
static constexpr int NSUB   = 500;     // level-2 sub-ranges (100 nodes each)
static constexpr int SNODES = 100;
static constexpr int SCAP   = 3712;    // mean 3200 (+9 sigma)
static constexpr int SPP    = 25;      // subs per partition
static constexpr int SLICES = 24;      // part2 blocks per partition
static constexpr int CHUNK  = 4096;    // edges per part1/part2 block-chunk

// ---------- block reduction (256 threads, wave64) ----------
__device__ inline float block_reduce_256(float v) {
    __shared__ float s[4];
    int lane = threadIdx.x & 63, wid = threadIdx.x >> 6;
    #pragma unroll
    for (int o = 32; o > 0; o >>= 1) v += __shfl_down(v, o);
    if (lane == 0) s[wid] = v;
    __syncthreads();
    if (threadIdx.x == 0) {
        float t = 0.f;
        #pragma unroll
        for (int i = 0; i < 4; i++) t += s[i];
        return t;
    }
    return 0.f;
}

// ---------- pass 1: partition edges into NP dst-ranges ----------
// entry = (d<<16) | s   (both < 65536)
__global__ void __launch_bounds__(256) k_part1(
        const int* __restrict__ src, const int* __restrict__ dst,
        int* __restrict__ gcur, unsigned* __restrict__ buf1) {
    __shared__ int hist[NP], gbase[NP], lcur[NP];
    int tid = threadIdx.x;
    if (tid < NP) hist[tid] = 0;
    __syncthreads();
    int e0 = blockIdx.x * CHUNK;
    unsigned ent[16]; int bin[16];
    #pragma unroll
    for (int k = 0; k < 16; k++) {
        int e = e0 + k * 256 + tid;
        if (e < NE) {
            unsigned d = (unsigned)dst[e], s = (unsigned)src[e];
            ent[k] = (d << 16) | s;
            bin[k] = (int)(d / (unsigned)PNODES);
            atomicAdd(&hist[bin[k]], 1);
        } else bin[k] = -1;
    }
    __syncthreads();
    if (tid < NP) { gbase[tid] = atomicAdd(&gcur[tid], hist[tid]); lcur[tid] = 0; }
    __syncthreads();
    #pragma unroll
    for (int k = 0; k < 16; k++) {
        if (bin[k] >= 0) {
            int p = gbase[bin[k]] + atomicAdd(&lcur[bin[k]], 1);
            if (p < PCAP) buf1[(size_t)bin[k] * PCAP + p] = ent[k];
        }
    }
}

// ---------- pass 2: partition each level-1 bucket into SPP sub-ranges ----------
__global__ void __launch_bounds__(256) k_part2(
        const int* __restrict__ gcur, const unsigned* __restrict__ buf1,
        int* __restrict__ cur2, unsigned* __restrict__ buf2) {
    __shared__ int hist[SPP], gbase[SPP], lcur[SPP];
    int part = blockIdx.x / SLICES;
    int slice = blockIdx.x % SLICES;
    int count = min(gcur[part], PCAP);
    const unsigned* in = buf1 + (size_t)part * PCAP;
    int sub0 = part * SPP;
    int tid = threadIdx.x;
    for (int base = slice * CHUNK; base < count; base += SLICES * CHUNK) {
        if (tid < SPP) hist[tid] = 0;
        __syncthreads();
        unsigned ent[16]; int bin[16];
        #pragma unroll
        for (int k = 0; k < 16; k++) {
            int i = base + k * 256 + tid;
            if (i < count) {
                unsigned e = in[i];
                ent[k] = e;
                bin[k] = (int)((e >> 16) / (unsigned)SNODES) - sub0;
                atomicAdd(&hist[bin[k]], 1);
            } else bin[k] = -1;
        }
        __syncthreads();
        if (tid < SPP) { gbase[tid] = atomicAdd(&cur2[sub0 + tid], hist[tid]); lcur[tid] = 0; }
        __syncthreads();
        #pragma unroll
        for (int k = 0; k < 16; k++) {
            if (bin[k] >= 0) {
                int p = gbase[bin[k]] + atomicAdd(&lcur[bin[k]], 1);
                if (p < SCAP) buf2[(size_t)(sub0 + bin[k]) * SCAP + p] = ent[k];
            }
        }
        __syncthreads();
    }
}

// ---------- per-sub-range degree histogram -> cnt (edges) + dinv ----------
__global__ void __launch_bounds__(256) k_hist(
        const int* __restrict__ cur2, const unsigned* __restrict__ buf2,
        int* __restrict__ cnt, float* __restrict__ dinv) {
    __shared__ int hist[SNODES];
    int tid = threadIdx.x, sub = blockIdx.x, vbase = sub * SNODES;
    for (int i = tid; i < SNODES; i += 256) hist[i] = 0;
    __syncthreads();
    int count = min(cur2[sub], SCAP);
    const unsigned* in = buf2 + (size_t)sub * SCAP;
    for (int i = tid; i < count; i += 256)
        atomicAdd(&hist[(int)(in[i] >> 16) - vbase], 1);
    __syncthreads();
    for (int v = tid; v < SNODES; v += 256) {
        int c = hist[v];
        cnt[vbase + v] = c;
        dinv[vbase + v] = rsqrtf((float)(4 * c + 1));
    }
}

// ---------- z1 = dinv * (x(batch0) @ W1); 4 threads per node ----------
__global__ void __launch_bounds__(256) k_xw1z(
        const float* __restrict__ x, const float* __restrict__ W1,
        const float* __restrict__ dinv, float* __restrict__ z) {
    __shared__ float sWT[FN * HD];   // [j][feat]: sWT[j*64+f] = W1[f*16+j]
    int tid = threadIdx.x;
    for (int i = tid; i < FN * HD; i += 256) {
        int j = i >> 6, f = i & 63;
        sWT[i] = W1[f * HD + j];
    }
    __syncthreads();
    int n = blockIdx.x * 64 + (tid >> 2);
    int q = tid & 3;
    if (n >= NN) return;
    const float4* xf = (const float4*)(x + (size_t)n * FN + q * 16);
    float4 f0 = xf[0], f1 = xf[1], f2 = xf[2], f3 = xf[3];
    int fb = q * 16;
    float t1[HD];
    #pragma unroll
    for (int j = 0; j < HD; j++) {
        const float* wr = &sWT[j * FN + fb];
        float a;
        a  = f0.x * wr[0]  + f0.y * wr[1]  + f0.z * wr[2]  + f0.w * wr[3];
        a += f1.x * wr[4]  + f1.y * wr[5]  + f1.z * wr[6]  + f1.w * wr[7];
        a += f2.x * wr[8]  + f2.y * wr[9]  + f2.z * wr[10] + f2.w * wr[11];
        a += f3.x * wr[12] + f3.y * wr[13] + f3.z * wr[14] + f3.w * wr[15];
        t1[j] = a;
    }
    #pragma unroll
    for (int j = 0; j < HD; j++) {
        t1[j] += __shfl_xor(t1[j], 1);
        t1[j] += __shfl_xor(t1[j], 2);
    }
    float dv = dinv[n];
    float4 o = make_float4(dv * t1[q*4+0], dv * t1[q*4+1], dv * t1[q*4+2], dv * t1[q*4+3]);
    ((float4*)(z + (size_t)n * HD))[q] = o;
}

// ---------- in-LDS counting sort using precomputed cnt + parallel scan ----------
__device__ inline void sort_sublist(int sub, const int* __restrict__ cur2,
                                    const int* __restrict__ cnt,
                                    const unsigned* __restrict__ buf2,
                                    unsigned* sorted, int* rp, int* cur, int* s) {
    int tid = threadIdx.x, vbase = sub * SNODES;
    int own = (tid < SNODES) ? cnt[vbase + tid] : 0;
    if (tid < 128) s[tid] = own;
    __syncthreads();
    #pragma unroll
    for (int off = 1; off < 128; off <<= 1) {
        int v = (tid < 128 && tid >= off) ? s[tid - off] : 0;
        __syncthreads();
        if (tid < 128) s[tid] += v;
        __syncthreads();
    }
    if (tid < SNODES) {
        int excl = s[tid] - own;
        rp[tid] = excl;
        cur[tid] = excl;
    }
    if (tid == SNODES - 1) rp[SNODES] = s[tid];
    __syncthreads();
    int count = min(cur2[sub], SCAP);
    const unsigned* in = buf2 + (size_t)sub * SCAP;
    for (int i = tid; i < count; i += 256) {
        unsigned e = in[i];
        int p = atomicAdd(&cur[(int)(e >> 16) - vbase], 1);
        sorted[p] = e;
    }
    __syncthreads();
}

// ---------- per-node register gather over a sorted run ----------
__device__ inline float gather_run(const unsigned* sorted, int s0, int s1,
                                   const float* __restrict__ z, int j) {
    float acc = 0.f;
    int i = s0;
    for (; i + 4 <= s1; i += 4) {
        unsigned a = sorted[i], b = sorted[i+1], c = sorted[i+2], d = sorted[i+3];
        float va = z[(a & 0xffffu) * HD + j];
        float vb = z[(b & 0xffffu) * HD + j];
        float vc = z[(c & 0xffffu) * HD + j];
        float vd = z[(d & 0xffffu) * HD + j];
        acc += (va + vb) + (vc + vd);
    }
    for (; i < s1; i++) acc += z[(sorted[i] & 0xffffu) * HD + j];
    return acc;
}

// ---------- conv1: sort + gather z1, finalize, z2 = dinv*(relu(.)@W2) ----------
__global__ void __launch_bounds__(256) k_conv1(
        const int* __restrict__ cur2, const int* __restrict__ cnt,
        const unsigned* __restrict__ buf2,
        const float* __restrict__ dinv, const float* __restrict__ z1,
        const float* __restrict__ b1, const float* __restrict__ W2,
        float* __restrict__ z2) {
    __shared__ unsigned sorted[SCAP];
    __shared__ int rp[SNODES + 1], cur[SNODES], s[128];
    __shared__ float sW[HD * HD], sb[HD];
    int tid = threadIdx.x;
    if (tid < HD * HD) sW[tid] = W2[tid];
    if (tid < HD) sb[tid] = b1[tid];
    int sub = blockIdx.x, vbase = sub * SNODES;
    sort_sublist(sub, cur2, cnt, buf2, sorted, rp, cur, s);

    int j = tid & 15, g = tid >> 4;
    int sbase = (tid & 63) & 48;
    #pragma unroll
    for (int it = 0; it < (SNODES + 15) / 16; it++) {
        int lv = it * 16 + g;
        bool valid = (lv < SNODES);
        float h = 0.f, dv = 0.f;
        if (valid) {
            float acc = gather_run(sorted, rp[lv], rp[lv + 1], z1, j);
            int v = vbase + lv;
            dv = dinv[v];
            h = fmaxf(4.f * dv * acc + dv * z1[v * HD + j] + sb[j], 0.f);
        }
        float o = 0.f;
        #pragma unroll
        for (int k = 0; k < HD; k++) o += __shfl(h, sbase + k) * sW[k * HD + j];
        if (valid) z2[(vbase + lv) * HD + j] = dv * o;
    }
}

// ---------- conv2: sort + gather z2, finalize, dot nfcW, reduce into sums[0] ----------
__global__ void __launch_bounds__(256) k_conv2(
        const int* __restrict__ cur2, const int* __restrict__ cnt,
        const unsigned* __restrict__ buf2,
        const float* __restrict__ dinv, const float* __restrict__ z2,
        const float* __restrict__ b2, const float* __restrict__ nfcW,
        double* __restrict__ sums) {
    __shared__ unsigned sorted[SCAP];
    __shared__ int rp[SNODES + 1], cur[SNODES], s[128];
    __shared__ float sb[HD], sw[HD];
    int tid = threadIdx.x;
    if (tid < HD) { sb[tid] = b2[tid]; sw[tid] = nfcW[tid]; }
    int sub = blockIdx.x, vbase = sub * SNODES;
    sort_sublist(sub, cur2, cnt, buf2, sorted, rp, cur, s);

    int j = tid & 15, g = tid >> 4;
    float part = 0.f;
    #pragma unroll
    for (int it = 0; it < (SNODES + 15) / 16; it++) {
        int lv = it * 16 + g;
        if (lv < SNODES) {
            float acc = gather_run(sorted, rp[lv], rp[lv + 1], z2, j);
            int v = vbase + lv;
            float dv = dinv[v];
            float h = fmaxf(4.f * dv * acc + dv * z2[v * HD + j] + sb[j], 0.f);
            part += h * sw[j];
        }
    }
    float bs = block_reduce_256(part);
    if (tid == 0) atomicAdd(&sums[0], (double)bs);
}

// ---------- batches 1..3: per-node MLP, 4 threads per node ----------
__global__ void __launch_bounds__(256) k_mlp(const float* __restrict__ x,
        const float* __restrict__ W1, const float* __restrict__ b1,
        const float* __restrict__ W2, const float* __restrict__ b2,
        const float* __restrict__ nfcW, double* __restrict__ sums) {
    __shared__ float sWT[FN * HD];   // [j][feat]
    __shared__ float sW2[HD * HD];
    __shared__ float sb1[HD], sb2[HD], sw[HD];
    int tid = threadIdx.x;
    for (int i = tid; i < FN * HD; i += 256) {
        int j = i >> 6, f = i & 63;
        sWT[i] = W1[f * HD + j];
    }
    if (tid < HD * HD) sW2[tid] = W2[tid];
    if (tid < HD) { sb1[tid] = b1[tid]; sb2[tid] = b2[tid]; sw[tid] = nfcW[tid]; }
    __syncthreads();
    int b = blockIdx.y + 1;
    int n = blockIdx.x * 64 + (tid >> 2);
    int q = tid & 3;
    float sv = 0.f;
    if (n < NN) {
        const float4* xf = (const float4*)(x + ((size_t)b * NN + n) * FN + q * 16);
        float4 f0 = xf[0], f1 = xf[1], f2 = xf[2], f3 = xf[3];
        int fb = q * 16;
        float t1[HD];
        #pragma unroll
        for (int j = 0; j < HD; j++) {
            const float* wr = &sWT[j * FN + fb];
            float a;
            a  = f0.x * wr[0]  + f0.y * wr[1]  + f0.z * wr[2]  + f0.w * wr[3];
            a += f1.x * wr[4]  + f1.y * wr[5]  + f1.z * wr[6]  + f1.w * wr[7];
            a += f2.x * wr[8]  + f2.y * wr[9]  + f2.z * wr[10] + f2.w * wr[11];
            a += f3.x * wr[12] + f3.y * wr[13] + f3.z * wr[14] + f3.w * wr[15];
            t1[j] = a;
        }
        #pragma unroll
        for (int j = 0; j < HD; j++) {
            t1[j] += __shfl_xor(t1[j], 1);
            t1[j] += __shfl_xor(t1[j], 2);
            t1[j] = fmaxf(t1[j] + sb1[j], 0.f);
        }
        #pragma unroll
        for (int kk = 0; kk < 4; kk++) {
            int k = q * 4 + kk;
            float t2 = sb2[k];
            #pragma unroll
            for (int j = 0; j < HD; j++) t2 += t1[j] * sW2[j * HD + k];
            sv += fmaxf(t2, 0.f) * sw[k];
        }
    }
    float bs = block_reduce_256(sv);
    if (tid == 0) atomicAdd(&sums[b], (double)bs);
}

// ---------- col path ----------
__global__ void k_col(const float* __restrict__ col, const float* __restrict__ cW1,
                      const float* __restrict__ cb1, const float* __restrict__ cW2,
                      double* __restrict__ sums) {
    __shared__ float sW1[FCOL * HD];
    __shared__ float sb1[HD], sw2[HD];
    for (int i = threadIdx.x; i < FCOL * HD; i += blockDim.x) sW1[i] = cW1[i];
    if (threadIdx.x < HD) { sb1[threadIdx.x] = cb1[threadIdx.x]; sw2[threadIdx.x] = cW2[threadIdx.x]; }
    __syncthreads();
    int b = blockIdx.y;
    int c = blockIdx.x * blockDim.x + threadIdx.x;
    float sv = 0.f;
    if (c < NC) {
        const float4* cf = (const float4*)(col + ((size_t)b * NC + c) * FCOL);
        float h[HD];
        #pragma unroll
        for (int j = 0; j < HD; j++) h[j] = sb1[j];
        #pragma unroll
        for (int k4 = 0; k4 < FCOL / 4; k4++) {
            float4 f = cf[k4];
            #pragma unroll
            for (int j = 0; j < HD; j++) {
                h[j] += f.x * sW1[(4 * k4 + 0) * HD + j];
                h[j] += f.y * sW1[(4 * k4 + 1) * HD + j];
                h[j] += f.z * sW1[(4 * k4 + 2) * HD + j];
                h[j] += f.w * sW1[(4 * k4 + 3) * HD + j];
            }
        }
        #pragma unroll
        for (int j = 0; j < HD; j++) sv += fmaxf(h[j], 0.f) * sw2[j];
    }
    float bs = block_reduce_256(sv);
    if (threadIdx.x == 0) atomicAdd(&sums[4 + b], (double)bs);
}

// ---------- final tiny head (adds folded biases) ----------
__global__ void k_final(const double* __restrict__ sums,
                        const float* __restrict__ nfcb, const float* __restrict__ cb2,
                        const float* __restrict__ fcW, const float* __restrict__ fcb,
                        const float* __restrict__ outW, const float* __restrict__ outb,
                        float* __restrict__ out) {
    int b = threadIdx.x;
    if (b < NBAT) {
        float na = (float)(sums[b] * (1.0 / NN)) + nfcb[0];
        float ca = (float)(sums[4 + b] * (1.0 / NC)) + cb2[0];
        float o = outb[0];
        #pragma unroll
        for (int j = 0; j < HD; j++) {
            float z = fmaxf(na * fcW[j] + ca * fcW[HD + j] + fcb[j], 0.f);
            o += z * outW[j];
        }
        out[b] = o;
    }
}

extern "C" void kernel_launch(void* const* d_in, const int* in_sizes, int n_in,
                              void* d_out, int out_size, void* d_ws, size_t ws_size,
                              hipStream_t stream) {
    const float* x    = (const float*)d_in[0];
    const float* col  = (const float*)d_in[1];
    const int*   ei   = (const int*)d_in[2];
    const float* W1   = (const float*)d_in[3];
    const float* b1   = (const float*)d_in[4];
    const float* W2   = (const float*)d_in[5];
    const float* b2   = (const float*)d_in[6];
    const float* nfcW = (const float*)d_in[7];
    const float* nfcb = (const float*)d_in[8];
    const float* cW1  = (const float*)d_in[9];
    const float* cb1  = (const float*)d_in[10];
    const float* cW2  = (const float*)d_in[11];
    const float* cb2  = (const float*)d_in[12];
    const float* fcW  = (const float*)d_in[13];
    const float* fcb  = (const float*)d_in[14];
    const float* outW = (const float*)d_in[15];
    const float* outb = (const float*)d_in[16];
    float* out = (float*)d_out;

    char* ws = (char*)d_ws;
    int*      gcur = (int*)     (ws + 0);          // 20 int
    int*      cur2 = (int*)     (ws + 128);        // 500 int -> ends 2128
    int*      cnt  = (int*)     (ws + 2176);       // 200000 B -> ends 202176
    float*    dinv = (float*)   (ws + 202176);     // 200000 B -> ends 402176
    unsigned* buf1 = (unsigned*)(ws + 402432);     // 7,040,000 B -> ends 7,442,432
    float*    z1   = (float*)   (ws + 402432);     // overlay on buf1 (dead after part2)
    float*    z2   = (float*)   (ws + 3602432);    // overlay on buf1 -> ends 6,802,432
    unsigned* buf2 = (unsigned*)(ws + 7442432);    // 7,424,000 B -> ends 14,866,432
    double*   sums = (double*)  (ws + 14866432);   // 8 doubles

    const int* src = ei;
    const int* dst = ei + NE;

    hipMemsetAsync(gcur, 0, 2128, stream);                 // gcur + cur2
    hipMemsetAsync(sums, 0, 8 * sizeof(double), stream);

    k_part1<<<(NE + CHUNK - 1) / CHUNK, 256, 0, stream>>>(src, dst, gcur, buf1);
    k_part2<<<NP * SLICES, 256, 0, stream>>>(gcur, buf1, cur2, buf2);
    k_hist <<<NSUB, 256, 0, stream>>>(cur2, buf2, cnt, dinv);
    k_xw1z <<<(NN + 63) / 64, 256, 0, stream>>>(x, W1, dinv, z1);
    k_conv1<<<NSUB, 256, 0, stream>>>(cur2, cnt, buf2, dinv, z1, b1, W2, z2);
    k_conv2<<<NSUB, 256, 0, stream>>>(cur2, cnt, buf2, dinv, z2, b2, nfcW, sums);

    dim3 gmlp((NN + 63) / 64, NBAT - 1);
    k_mlp <<<gmlp, 256, 0, stream>>>(x, W1, b1, W2, b2, nfcW, sums);
    dim3 gcol((NC + 255) / 256, NBAT);
    k_col <<<gcol, 256, 0, stream>>>(col, cW1, cb1, cW2, sums);
    k_final<<<1, 64, 0, stream>>>(sums, nfcb, cb2, fcW, fcb, outW, outb, out);
}

// Round 6
// 149.126 us; speedup vs baseline: 1.0745x; 1.0745x over previous
//
#include <hip/hip_runtime.h>

static constexpr int NN   = 50000;    // nodes per batch
static constexpr int NBAT = 4;
static constexpr int NE   = 1600000;  // unique edges
static constexpr int NC   = 1000;
static constexpr int FN   = 64;
static constexpr int FCOL = 32;
static constexpr int HD   = 16;

// two-level partition geometry
static constexpr int NP     = 20;      // level-1 partitions (2500 nodes each)
static constexpr int PNODES = 2500;
static constexpr int PCAP   = 88000;   // mean 80000 (+29 sigma)
static constexpr int NSUB   = 500;     // level-2 sub-ranges (100 nodes each)
static constexpr int SNODES = 100;
static constexpr int SCAP   = 3712;    // mean 3200 (+9 sigma)
static constexpr int SPP    = 25;      // subs per partition
static constexpr int SLICES = 24;      // part2 blocks per partition
static constexpr int CHUNK  = 4096;    // edges per part1/part2 block-chunk

// fused MLP tile geometry
static constexpr int TILE = 192;       // nodes per block-tile
static constexpr int NPT  = 3;         // nodes per thread
static constexpr int XPAD = 68;        // x-tile row stride (floats): 68%32=4 -> spreads banks

// ---------- block reduction (256 threads, wave64) ----------
__device__ inline float block_reduce_256(float v) {
    __shared__ float s[4];
    int lane = threadIdx.x & 63, wid = threadIdx.x >> 6;
    #pragma unroll
    for (int o = 32; o > 0; o >>= 1) v += __shfl_down(v, o);
    if (lane == 0) s[wid] = v;
    __syncthreads();
    if (threadIdx.x == 0) {
        float t = 0.f;
        #pragma unroll
        for (int i = 0; i < 4; i++) t += s[i];
        return t;
    }
    return 0.f;
}

// ---------- pass 1: partition edges into NP dst-ranges ----------
// entry = (d<<16) | s   (both < 65536)
__global__ void __launch_bounds__(256) k_part1(
        const int* __restrict__ src, const int* __restrict__ dst,
        int* __restrict__ gcur, unsigned* __restrict__ buf1) {
    __shared__ int hist[NP], gbase[NP], lcur[NP];
    int tid = threadIdx.x;
    if (tid < NP) hist[tid] = 0;
    __syncthreads();
    int e0 = blockIdx.x * CHUNK;
    unsigned ent[16]; int bin[16];
    #pragma unroll
    for (int k = 0; k < 16; k++) {
        int e = e0 + k * 256 + tid;
        if (e < NE) {
            unsigned d = (unsigned)dst[e], s = (unsigned)src[e];
            ent[k] = (d << 16) | s;
            bin[k] = (int)(d / (unsigned)PNODES);
            atomicAdd(&hist[bin[k]], 1);
        } else bin[k] = -1;
    }
    __syncthreads();
    if (tid < NP) { gbase[tid] = atomicAdd(&gcur[tid], hist[tid]); lcur[tid] = 0; }
    __syncthreads();
    #pragma unroll
    for (int k = 0; k < 16; k++) {
        if (bin[k] >= 0) {
            int p = gbase[bin[k]] + atomicAdd(&lcur[bin[k]], 1);
            if (p < PCAP) buf1[(size_t)bin[k] * PCAP + p] = ent[k];
        }
    }
}

// ---------- pass 2: partition each level-1 bucket into SPP sub-ranges ----------
__global__ void __launch_bounds__(256) k_part2(
        const int* __restrict__ gcur, const unsigned* __restrict__ buf1,
        int* __restrict__ cur2, unsigned* __restrict__ buf2) {
    __shared__ int hist[SPP], gbase[SPP], lcur[SPP];
    int part = blockIdx.x / SLICES;
    int slice = blockIdx.x % SLICES;
    int count = min(gcur[part], PCAP);
    const unsigned* in = buf1 + (size_t)part * PCAP;
    int sub0 = part * SPP;
    int tid = threadIdx.x;
    for (int base = slice * CHUNK; base < count; base += SLICES * CHUNK) {
        if (tid < SPP) hist[tid] = 0;
        __syncthreads();
        unsigned ent[16]; int bin[16];
        #pragma unroll
        for (int k = 0; k < 16; k++) {
            int i = base + k * 256 + tid;
            if (i < count) {
                unsigned e = in[i];
                ent[k] = e;
                bin[k] = (int)((e >> 16) / (unsigned)SNODES) - sub0;
                atomicAdd(&hist[bin[k]], 1);
            } else bin[k] = -1;
        }
        __syncthreads();
        if (tid < SPP) { gbase[tid] = atomicAdd(&cur2[sub0 + tid], hist[tid]); lcur[tid] = 0; }
        __syncthreads();
        #pragma unroll
        for (int k = 0; k < 16; k++) {
            if (bin[k] >= 0) {
                int p = gbase[bin[k]] + atomicAdd(&lcur[bin[k]], 1);
                if (p < SCAP) buf2[(size_t)(sub0 + bin[k]) * SCAP + p] = ent[k];
            }
        }
        __syncthreads();
    }
}

// ---------- per-sub-range degree histogram -> cnt (edges) + dinv ----------
__global__ void __launch_bounds__(256) k_hist(
        const int* __restrict__ cur2, const unsigned* __restrict__ buf2,
        int* __restrict__ cnt, float* __restrict__ dinv) {
    __shared__ int hist[SNODES];
    int tid = threadIdx.x, sub = blockIdx.x, vbase = sub * SNODES;
    for (int i = tid; i < SNODES; i += 256) hist[i] = 0;
    __syncthreads();
    int count = min(cur2[sub], SCAP);
    const unsigned* in = buf2 + (size_t)sub * SCAP;
    for (int i = tid; i < count; i += 256)
        atomicAdd(&hist[(int)(in[i] >> 16) - vbase], 1);
    __syncthreads();
    for (int v = tid; v < SNODES; v += 256) {
        int c = hist[v];
        cnt[vbase + v] = c;
        dinv[vbase + v] = rsqrtf((float)(4 * c + 1));
    }
}

// ---------- fused: all 4 batches x@W1; b==0 -> z1 = dinv*(x@W1); b>0 -> full MLP reduce ----------
// block = 256 threads = 64 node-groups x 4 j-quads; tile = 192 nodes staged in LDS.
__global__ void __launch_bounds__(256) k_xmlp(
        const float* __restrict__ x, const float* __restrict__ dinv,
        const float* __restrict__ W1, const float* __restrict__ b1,
        const float* __restrict__ W2, const float* __restrict__ b2,
        const float* __restrict__ nfcW,
        float* __restrict__ z1, double* __restrict__ sums) {
    __shared__ float sx[TILE * XPAD];     // 52224 B
    __shared__ float sw1[FN * HD];        // 4096 B, natural [k][j]
    __shared__ float sw2t[HD * HD];       // 1024 B, sw2t[k*16+j] = W2[j*16+k]
    __shared__ float sb1[HD], sb2[HD], snf[HD];
    int tid = threadIdx.x;
    int b = blockIdx.y;
    int tile0 = blockIdx.x * TILE;

    for (int i = tid; i < FN * HD; i += 256) sw1[i] = W1[i];
    sw2t[tid] = W2[(tid & 15) * HD + (tid >> 4)];
    if (tid < HD) { sb1[tid] = b1[tid]; sb2[tid] = b2[tid]; snf[tid] = nfcW[tid]; }

    // stage x tile, zero-padded past NN (coalesced float4)
    const float* xb = x + (size_t)b * NN * FN;
    #pragma unroll
    for (int it = 0; it < TILE * 16 / 256; it++) {   // 12
        int idx = it * 256 + tid;
        int node = idx >> 4, c4 = idx & 15;
        int g = tile0 + node;
        float4 v = make_float4(0.f, 0.f, 0.f, 0.f);
        if (g < NN) v = *(const float4*)&xb[(size_t)g * FN + c4 * 4];
        *(float4*)&sx[node * XPAD + c4 * 4] = v;
    }
    __syncthreads();

    int jg = tid & 3, ng = tid >> 2;
    int nl0 = ng * NPT;
    float acc[NPT][4];
    #pragma unroll
    for (int c = 0; c < NPT; c++)
        #pragma unroll
        for (int i = 0; i < 4; i++) acc[c][i] = 0.f;

    #pragma unroll
    for (int kc = 0; kc < 16; kc++) {
        float xr[NPT][4], wr[4][4];
        #pragma unroll
        for (int c = 0; c < NPT; c++)
            *(float4*)&xr[c][0] = *(const float4*)&sx[(nl0 + c) * XPAD + kc * 4];
        #pragma unroll
        for (int i = 0; i < 4; i++)
            *(float4*)&wr[i][0] = *(const float4*)&sw1[(kc * 4 + i) * HD + jg * 4];
        #pragma unroll
        for (int c = 0; c < NPT; c++)
            #pragma unroll
            for (int jj = 0; jj < 4; jj++)
                acc[c][jj] += xr[c][0] * wr[0][jj] + xr[c][1] * wr[1][jj]
                            + xr[c][2] * wr[2][jj] + xr[c][3] * wr[3][jj];
    }

    if (b == 0) {
        #pragma unroll
        for (int c = 0; c < NPT; c++) {
            int g = tile0 + nl0 + c;
            if (g < NN) {
                float dv = dinv[g];
                float4 o = make_float4(dv * acc[c][0], dv * acc[c][1],
                                       dv * acc[c][2], dv * acc[c][3]);
                *(float4*)&z1[(size_t)g * HD + jg * 4] = o;
            }
        }
    } else {
        float sv = 0.f;
        #pragma unroll
        for (int c = 0; c < NPT; c++) {
            int g = tile0 + nl0 + c;
            bool valid = (g < NN);
            float h0 = fmaxf(acc[c][0] + sb1[jg * 4 + 0], 0.f);
            float h1 = fmaxf(acc[c][1] + sb1[jg * 4 + 1], 0.f);
            float h2 = fmaxf(acc[c][2] + sb1[jg * 4 + 2], 0.f);
            float h3 = fmaxf(acc[c][3] + sb1[jg * 4 + 3], 0.f);
            #pragma unroll
            for (int k = 0; k < HD; k++) {
                const float* w2r = &sw2t[k * HD + jg * 4];
                float pk = h0 * w2r[0] + h1 * w2r[1] + h2 * w2r[2] + h3 * w2r[3];
                pk += __shfl_xor(pk, 1);
                pk += __shfl_xor(pk, 2);
                if ((k >> 2) == jg && valid)
                    sv += fmaxf(pk + sb2[k], 0.f) * snf[k];
            }
        }
        float bs = block_reduce_256(sv);
        if (tid == 0) atomicAdd(&sums[b], (double)bs);
    }
}

// ---------- in-LDS counting sort using precomputed cnt + parallel scan ----------
__device__ inline void sort_sublist(int sub, const int* __restrict__ cur2,
                                    const int* __restrict__ cnt,
                                    const unsigned* __restrict__ buf2,
                                    unsigned* sorted, int* rp, int* cur, int* s) {
    int tid = threadIdx.x, vbase = sub * SNODES;
    int own = (tid < SNODES) ? cnt[vbase + tid] : 0;
    if (tid < 128) s[tid] = own;
    __syncthreads();
    #pragma unroll
    for (int off = 1; off < 128; off <<= 1) {
        int v = (tid < 128 && tid >= off) ? s[tid - off] : 0;
        __syncthreads();
        if (tid < 128) s[tid] += v;
        __syncthreads();
    }
    if (tid < SNODES) {
        int excl = s[tid] - own;
        rp[tid] = excl;
        cur[tid] = excl;
    }
    if (tid == SNODES - 1) rp[SNODES] = s[tid];
    __syncthreads();
    int count = min(cur2[sub], SCAP);
    const unsigned* in = buf2 + (size_t)sub * SCAP;
    for (int i = tid; i < count; i += 256) {
        unsigned e = in[i];
        int p = atomicAdd(&cur[(int)(e >> 16) - vbase], 1);
        sorted[p] = e;
    }
    __syncthreads();
}

// ---------- per-node register gather over a sorted run ----------
__device__ inline float gather_run(const unsigned* sorted, int s0, int s1,
                                   const float* __restrict__ z, int j) {
    float acc = 0.f;
    int i = s0;
    for (; i + 4 <= s1; i += 4) {
        unsigned a = sorted[i], b = sorted[i+1], c = sorted[i+2], d = sorted[i+3];
        float va = z[(a & 0xffffu) * HD + j];
        float vb = z[(b & 0xffffu) * HD + j];
        float vc = z[(c & 0xffffu) * HD + j];
        float vd = z[(d & 0xffffu) * HD + j];
        acc += (va + vb) + (vc + vd);
    }
    for (; i < s1; i++) acc += z[(sorted[i] & 0xffffu) * HD + j];
    return acc;
}

// ---------- conv1: sort + gather z1, finalize, z2 = dinv*(relu(.)@W2) ----------
__global__ void __launch_bounds__(256) k_conv1(
        const int* __restrict__ cur2, const int* __restrict__ cnt,
        const unsigned* __restrict__ buf2,
        const float* __restrict__ dinv, const float* __restrict__ z1,
        const float* __restrict__ b1, const float* __restrict__ W2,
        float* __restrict__ z2) {
    __shared__ unsigned sorted[SCAP];
    __shared__ int rp[SNODES + 1], cur[SNODES], s[128];
    __shared__ float sW[HD * HD], sb[HD];
    int tid = threadIdx.x;
    if (tid < HD * HD) sW[tid] = W2[tid];
    if (tid < HD) sb[tid] = b1[tid];
    int sub = blockIdx.x, vbase = sub * SNODES;
    sort_sublist(sub, cur2, cnt, buf2, sorted, rp, cur, s);

    int j = tid & 15, g = tid >> 4;
    int sbase = (tid & 63) & 48;
    #pragma unroll
    for (int it = 0; it < (SNODES + 15) / 16; it++) {
        int lv = it * 16 + g;
        bool valid = (lv < SNODES);
        float h = 0.f, dv = 0.f;
        if (valid) {
            float acc = gather_run(sorted, rp[lv], rp[lv + 1], z1, j);
            int v = vbase + lv;
            dv = dinv[v];
            h = fmaxf(4.f * dv * acc + dv * z1[v * HD + j] + sb[j], 0.f);
        }
        float o = 0.f;
        #pragma unroll
        for (int k = 0; k < HD; k++) o += __shfl(h, sbase + k) * sW[k * HD + j];
        if (valid) z2[(vbase + lv) * HD + j] = dv * o;
    }
}

// ---------- conv2: sort + gather z2, finalize, dot nfcW, reduce into sums[0] ----------
__global__ void __launch_bounds__(256) k_conv2(
        const int* __restrict__ cur2, const int* __restrict__ cnt,
        const unsigned* __restrict__ buf2,
        const float* __restrict__ dinv, const float* __restrict__ z2,
        const float* __restrict__ b2, const float* __restrict__ nfcW,
        double* __restrict__ sums) {
    __shared__ unsigned sorted[SCAP];
    __shared__ int rp[SNODES + 1], cur[SNODES], s[128];
    __shared__ float sb[HD], sw[HD];
    int tid = threadIdx.x;
    if (tid < HD) { sb[tid] = b2[tid]; sw[tid] = nfcW[tid]; }
    int sub = blockIdx.x, vbase = sub * SNODES;
    sort_sublist(sub, cur2, cnt, buf2, sorted, rp, cur, s);

    int j = tid & 15, g = tid >> 4;
    float part = 0.f;
    #pragma unroll
    for (int it = 0; it < (SNODES + 15) / 16; it++) {
        int lv = it * 16 + g;
        if (lv < SNODES) {
            float acc = gather_run(sorted, rp[lv], rp[lv + 1], z2, j);
            int v = vbase + lv;
            float dv = dinv[v];
            float h = fmaxf(4.f * dv * acc + dv * z2[v * HD + j] + sb[j], 0.f);
            part += h * sw[j];
        }
    }
    float bs = block_reduce_256(part);
    if (tid == 0) atomicAdd(&sums[0], (double)bs);
}

// ---------- col path ----------
__global__ void k_col(const float* __restrict__ col, const float* __restrict__ cW1,
                      const float* __restrict__ cb1, const float* __restrict__ cW2,
                      double* __restrict__ sums) {
    __shared__ float sW1[FCOL * HD];
    __shared__ float sb1[HD], sw2[HD];
    for (int i = threadIdx.x; i < FCOL * HD; i += blockDim.x) sW1[i] = cW1[i];
    if (threadIdx.x < HD) { sb1[threadIdx.x] = cb1[threadIdx.x]; sw2[threadIdx.x] = cW2[threadIdx.x]; }
    __syncthreads();
    int b = blockIdx.y;
    int c = blockIdx.x * blockDim.x + threadIdx.x;
    float sv = 0.f;
    if (c < NC) {
        const float4* cf = (const float4*)(col + ((size_t)b * NC + c) * FCOL);
        float h[HD];
        #pragma unroll
        for (int j = 0; j < HD; j++) h[j] = sb1[j];
        #pragma unroll
        for (int k4 = 0; k4 < FCOL / 4; k4++) {
            float4 f = cf[k4];
            #pragma unroll
            for (int j = 0; j < HD; j++) {
                h[j] += f.x * sW1[(4 * k4 + 0) * HD + j];
                h[j] += f.y * sW1[(4 * k4 + 1) * HD + j];
                h[j] += f.z * sW1[(4 * k4 + 2) * HD + j];
                h[j] += f.w * sW1[(4 * k4 + 3) * HD + j];
            }
        }
        #pragma unroll
        for (int j = 0; j < HD; j++) sv += fmaxf(h[j], 0.f) * sw2[j];
    }
    float bs = block_reduce_256(sv);
    if (threadIdx.x == 0) atomicAdd(&sums[4 + b], (double)bs);
}

// ---------- final tiny head (adds folded biases) ----------
__global__ void k_final(const double* __restrict__ sums,
                        const float* __restrict__ nfcb, const float* __restrict__ cb2,
                        const float* __restrict__ fcW, const float* __restrict__ fcb,
                        const float* __restrict__ outW, const float* __restrict__ outb,
                        float* __restrict__ out) {
    int b = threadIdx.x;
    if (b < NBAT) {
        float na = (float)(sums[b] * (1.0 / NN)) + nfcb[0];
        float ca = (float)(sums[4 + b] * (1.0 / NC)) + cb2[0];
        float o = outb[0];
        #pragma unroll
        for (int j = 0; j < HD; j++) {
            float z = fmaxf(na * fcW[j] + ca * fcW[HD + j] + fcb[j], 0.f);
            o += z * outW[j];
        }
        out[b] = o;
    }
}

extern "C" void kernel_launch(void* const* d_in, const int* in_sizes, int n_in,
                              void* d_out, int out_size, void* d_ws, size_t ws_size,
                              hipStream_t stream) {
    const float* x    = (const float*)d_in[0];
    const float* col  = (const float*)d_in[1];
    const int*   ei   = (const int*)d_in[2];
    const float* W1   = (const float*)d_in[3];
    const float* b1   = (const float*)d_in[4];
    const float* W2   = (const float*)d_in[5];
    const float* b2   = (const float*)d_in[6];
    const float* nfcW = (const float*)d_in[7];
    const float* nfcb = (const float*)d_in[8];
    const float* cW1  = (const float*)d_in[9];
    const float* cb1  = (const float*)d_in[10];
    const float* cW2  = (const float*)d_in[11];
    const float* cb2  = (const float*)d_in[12];
    const float* fcW  = (const float*)d_in[13];
    const float* fcb  = (const float*)d_in[14];
    const float* outW = (const float*)d_in[15];
    const float* outb = (const float*)d_in[16];
    float* out = (float*)d_out;

    char* ws = (char*)d_ws;
    int*      gcur = (int*)     (ws + 0);          // 20 int
    int*      cur2 = (int*)     (ws + 128);        // 500 int -> ends 2128
    int*      cnt  = (int*)     (ws + 2176);       // 200000 B -> ends 202176
    float*    dinv = (float*)   (ws + 202176);     // 200000 B -> ends 402176
    unsigned* buf1 = (unsigned*)(ws + 402432);     // 7,040,000 B -> ends 7,442,432
    float*    z1   = (float*)   (ws + 402432);     // overlay on buf1 (dead after part2)
    float*    z2   = (float*)   (ws + 3602432);    // overlay on buf1 -> ends 6,802,432
    unsigned* buf2 = (unsigned*)(ws + 7442432);    // 7,424,000 B -> ends 14,866,432
    double*   sums = (double*)  (ws + 14866432);   // 8 doubles

    const int* src = ei;
    const int* dst = ei + NE;

    hipMemsetAsync(gcur, 0, 2128, stream);                 // gcur + cur2
    hipMemsetAsync(sums, 0, 8 * sizeof(double), stream);

    k_part1<<<(NE + CHUNK - 1) / CHUNK, 256, 0, stream>>>(src, dst, gcur, buf1);
    k_part2<<<NP * SLICES, 256, 0, stream>>>(gcur, buf1, cur2, buf2);
    k_hist <<<NSUB, 256, 0, stream>>>(cur2, buf2, cnt, dinv);

    dim3 gx((NN + TILE - 1) / TILE, NBAT);
    k_xmlp <<<gx, 256, 0, stream>>>(x, dinv, W1, b1, W2, b2, nfcW, z1, sums);

    k_conv1<<<NSUB, 256, 0, stream>>>(cur2, cnt, buf2, dinv, z1, b1, W2, z2);
    k_conv2<<<NSUB, 256, 0, stream>>>(cur2, cnt, buf2, dinv, z2, b2, nfcW, sums);

    dim3 gcol((NC + 255) / 256, NBAT);
    k_col <<<gcol, 256, 0, stream>>>(col, cW1, cb1, cW2, sums);
    k_final<<<1, 64, 0, stream>>>(sums, nfcb, cb2, fcW, fcb, outW, outb, out);
}